// Round 9
// baseline (950.109 us; speedup 1.0000x reference)
//
#include <hip/hip_runtime.h>
#include <hip/hip_bf16.h>
#include <cstdint>
#include <cstddef>

// ---------------------------------------------------------------------------
// MultiValGCN: out = log_softmax( adjcat @ relu(adjcat @ (x W1)cat + b1) W2cat + b2 )
// Round 9: k_gemm_h re-tiled 128x128 -> 256x256 (512 thr, 8 waves, per-wave
// 128x64, acc[8][4]): LDS-read B/FLOP 61->23, far-fetch B/FLOP 15.6->7.8.
// K-split 2 (grid 256 = 1 block/CU), f32 partials + reduce kernel. Sync
// structure unchanged (proven single-buffer, 2 barriers). Fallbacks kept.
// ---------------------------------------------------------------------------

typedef __bf16 bf16_t;
typedef __bf16 bf16x8 __attribute__((ext_vector_type(8)));
typedef __bf16 bf16x4 __attribute__((ext_vector_type(4)));
typedef float  f32x4  __attribute__((ext_vector_type(4)));

#define NROWS 8192
#define DIN   512
#define DHID  1024
#define DOUT  64
#define ORD   3
#define KTOT  24576   // ORD*NROWS

#define GLDS(g, l) __builtin_amdgcn_global_load_lds( \
    (__attribute__((address_space(1))) void*)(g),    \
    (__attribute__((address_space(3))) void*)(l), 16, 0, 0)

// LDS tile layout: [rows][8 slots of 8 bf16]; physical slot = logical ^ (row&7).
// GLDS writes linearly, so the GLOBAL source reads slot (lane&7)^(lane>>3).

// ---------------- x: f32 -> bf16 ----------------
__global__ void k_cvt_x(const float* __restrict__ x, bf16_t* __restrict__ xb) {
  int i = blockIdx.x * blockDim.x + threadIdx.x;            // one per 8 elems
  const float4* p = reinterpret_cast<const float4*>(x) + (size_t)i * 2;
  float4 v0 = p[0], v1 = p[1];
  bf16x8 o;
  o[0]=(bf16_t)v0.x; o[1]=(bf16_t)v0.y; o[2]=(bf16_t)v0.z; o[3]=(bf16_t)v0.w;
  o[4]=(bf16_t)v1.x; o[5]=(bf16_t)v1.y; o[6]=(bf16_t)v1.z; o[7]=(bf16_t)v1.w;
  *reinterpret_cast<bf16x8*>(xb + (size_t)i * 8) = o;
}

// ---------------- adj: f32 -> bf16, full 192M-element stream ----------------
__global__ void k_cvt_adj(const float* __restrict__ a, bf16_t* __restrict__ ab) {
  size_t i = (size_t)blockIdx.x * blockDim.x + threadIdx.x;  // one per 8 elems
  const size_t stride = (size_t)gridDim.x * blockDim.x;
  const float4* src = reinterpret_cast<const float4*>(a);
#pragma unroll 4
  for (int it = 0; it < 48; ++it, i += stride) {
    float4 v0 = src[i * 2], v1 = src[i * 2 + 1];
    bf16x8 o;
    o[0]=(bf16_t)v0.x; o[1]=(bf16_t)v0.y; o[2]=(bf16_t)v0.z; o[3]=(bf16_t)v0.w;
    o[4]=(bf16_t)v1.x; o[5]=(bf16_t)v1.y; o[6]=(bf16_t)v1.z; o[7]=(bf16_t)v1.w;
    *reinterpret_cast<bf16x8*>(ab + i * 8) = o;
  }
}

// ---------------- W transpose + cvt: src f32 [R][C] -> dst bf16 [C][R], per order z
__global__ void k_transpose_cvt(const float* __restrict__ src, bf16_t* __restrict__ dst,
                                int R, int C) {
  __shared__ float tile[64][65];
  int ord = blockIdx.z;
  src += (size_t)ord * R * C;
  dst += (size_t)ord * R * C;
  int c0 = blockIdx.x * 64, r0 = blockIdx.y * 64;
  for (int i = 0; i < 16; ++i) {
    int idx = i * 256 + threadIdx.x;
    int r = idx >> 6, c = idx & 63;
    tile[r][c] = src[(size_t)(r0 + r) * C + c0 + c];
  }
  __syncthreads();
  for (int i = 0; i < 16; ++i) {
    int idx = i * 256 + threadIdx.x;
    int cc = idx >> 6, rr = idx & 63;
    dst[(size_t)(c0 + cc) * R + r0 + rr] = (bf16_t)tile[rr][cc];
  }
}

// ---------------- K1: xw1T[o][ord*8192+n] = sum_i x(n,i) W1[ord](i,o)  (bf16)
__global__ __launch_bounds__(256) void k_gemm_xw1(
    const bf16_t* __restrict__ xb,    // [8192][512]
    const bf16_t* __restrict__ w1t,   // [3][1024][512]
    bf16_t* __restrict__ xw1t)        // [1024][24576]
{
  __shared__ bf16_t As[128 * 64];
  __shared__ bf16_t Bs[128 * 64];
  int ntile = blockIdx.x, mtile = blockIdx.y, ord = blockIdx.z;
  int tid = threadIdx.x, lane = tid & 63, wid = tid >> 6;
  int wm = wid >> 1, wn = wid & 1;
  int sl = (lane & 7) ^ (lane >> 3);              // pre-swizzled source slot
  f32x4 acc[4][4] = {};
  const bf16_t* w1o = w1t + (size_t)ord * DHID * DIN;
  for (int kt = 0; kt < DIN; kt += 64) {
    for (int j = 0; j < 4; ++j) {           // A: x rows, 16 KB
      int q = wid * 4 + j;
      int row = q * 8 + (lane >> 3);
      GLDS(xb + (size_t)(mtile * 128 + row) * DIN + kt + sl * 8, &As[q * 512]);
    }
    for (int j = 0; j < 4; ++j) {           // B: W1T rows (o), 16 KB
      int q = wid * 4 + j;
      int row = q * 8 + (lane >> 3);
      GLDS(w1o + (size_t)(ntile * 128 + row) * DIN + kt + sl * 8, &Bs[q * 512]);
    }
    __syncthreads();
    for (int ks = 0; ks < 2; ++ks) {
      int psl = ((ks << 2) + (lane >> 4)) ^ (lane & 7);
      bf16x8 a[4], b[4];
      for (int f = 0; f < 4; ++f)
        a[f] = *reinterpret_cast<const bf16x8*>(&As[(wm * 64 + f * 16 + (lane & 15)) * 64 + psl * 8]);
      for (int f = 0; f < 4; ++f)
        b[f] = *reinterpret_cast<const bf16x8*>(&Bs[(wn * 64 + f * 16 + (lane & 15)) * 64 + psl * 8]);
      for (int fm = 0; fm < 4; ++fm)
        for (int fn = 0; fn < 4; ++fn)
          acc[fm][fn] = __builtin_amdgcn_mfma_f32_16x16x32_bf16(a[fm], b[fn], acc[fm][fn], 0, 0, 0);
    }
    __syncthreads();
  }
  for (int fm = 0; fm < 4; ++fm)
    for (int fn = 0; fn < 4; ++fn) {
      int o  = ntile * 128 + wn * 64 + fn * 16 + (lane & 15);
      int n0 = mtile * 128 + wm * 64 + fm * 16 + ((lane >> 4) << 2);
      bf16x4 v;
      v[0] = (bf16_t)acc[fm][fn][0]; v[1] = (bf16_t)acc[fm][fn][1];
      v[2] = (bf16_t)acc[fm][fn][2]; v[3] = (bf16_t)acc[fm][fn][3];
      *reinterpret_cast<bf16x4*>(&xw1t[(size_t)o * KTOT + ord * NROWS + n0]) = v;
    }
}

// ---------------- K2: hpart[ksp] = adj[ksp-half] @ xw1. 256x256 tile, 8 waves.
// Decode: ksp = xcd&1; XCD-pair (xcd>>1) owns mtiles pair*8..pair*8+7 x 4 ntiles.
__global__ __launch_bounds__(512) void k_gemm_h256(
    const bf16_t* __restrict__ adjb,   // [3][8192][8192] bf16
    const bf16_t* __restrict__ xw1t,   // [1024][24576]
    float* __restrict__ hpart)         // [2][8192][1024] f32
{
  __shared__ bf16_t As[256 * 64];   // 32 KB
  __shared__ bf16_t Bs[256 * 64];   // 32 KB
  int d = blockIdx.x;               // 0..255
  int xcd = d & 7;
  int s = d >> 3;                   // 0..31
  int ksp = xcd & 1;
  int mtile = (xcd >> 1) * 8 + (s >> 2);   // 0..31
  int ntile = s & 3;                       // 0..3
  int tid = threadIdx.x, lane = tid & 63, wid = tid >> 6;   // wid 0..7
  int wm = wid >> 2, wn = wid & 3;         // 2M x 4N, per-wave 128x64
  int sl = (lane & 7) ^ (lane >> 3);
  const size_t NN = (size_t)NROWS * NROWS;
  f32x4 acc[8][4] = {};
  const int T0 = ksp * 192, NT = 192;

  for (int t = 0; t < NT; ++t) {
    int kk = (T0 + t) * 64;
    int ord = kk >> 13, mcol = kk & 8191;
    const bf16_t* ao = adjb + (size_t)ord * NN + (size_t)(mtile * 256) * NROWS + mcol;
#pragma unroll
    for (int j = 0; j < 4; ++j) {           // A: 256 adj rows, 32 KB (q 0..31)
      int q = wid * 4 + j;
      int row = q * 8 + (lane >> 3);
      GLDS(ao + (size_t)row * NROWS + sl * 8, &As[q * 512]);
    }
#pragma unroll
    for (int j = 0; j < 4; ++j) {           // B: 256 xw1T rows (o), 32 KB
      int q = wid * 4 + j;
      int row = q * 8 + (lane >> 3);
      GLDS(xw1t + (size_t)(ntile * 256 + row) * KTOT + kk + sl * 8, &Bs[q * 512]);
    }
    __syncthreads();
#pragma unroll
    for (int ks = 0; ks < 2; ++ks) {
      int psl = ((ks << 2) + (lane >> 4)) ^ (lane & 7);
      bf16x8 a[8], b[4];
#pragma unroll
      for (int f = 0; f < 8; ++f)
        a[f] = *reinterpret_cast<const bf16x8*>(&As[(wm * 128 + f * 16 + (lane & 15)) * 64 + psl * 8]);
#pragma unroll
      for (int f = 0; f < 4; ++f)
        b[f] = *reinterpret_cast<const bf16x8*>(&Bs[(wn * 64 + f * 16 + (lane & 15)) * 64 + psl * 8]);
#pragma unroll
      for (int fm = 0; fm < 8; ++fm)
#pragma unroll
        for (int fn = 0; fn < 4; ++fn)
          acc[fm][fn] = __builtin_amdgcn_mfma_f32_16x16x32_bf16(a[fm], b[fn], acc[fm][fn], 0, 0, 0);
    }
    __syncthreads();
  }

  float* pout = hpart + (size_t)ksp * NROWS * DHID;
#pragma unroll
  for (int fm = 0; fm < 8; ++fm)
#pragma unroll
    for (int fn = 0; fn < 4; ++fn) {
      int o  = ntile * 256 + wn * 64 + fn * 16 + (lane & 15);
      int n0 = mtile * 256 + wm * 128 + fm * 16 + ((lane >> 4) << 2);
      for (int j = 0; j < 4; ++j)
        pout[(size_t)(n0 + j) * DHID + o] = acc[fm][fn][j];
    }
}

// ---------------- reduce: h = relu(hpart0 + hpart1 + b1), bf16 ----------------
__global__ void k_reduce_h(const float* __restrict__ hpart, const float* __restrict__ b1,
                           bf16_t* __restrict__ h) {
  size_t i4 = (size_t)blockIdx.x * blockDim.x + threadIdx.x;   // one per 4 elems
  size_t base = i4 * 4;
  int col = (int)(base & (DHID - 1));
  const size_t S = (size_t)NROWS * DHID;
  float4 p0 = *reinterpret_cast<const float4*>(hpart + base);
  float4 p1 = *reinterpret_cast<const float4*>(hpart + S + base);
  float4 bb = *reinterpret_cast<const float4*>(b1 + col);
  bf16x4 v;
  float t0 = p0.x + p1.x + bb.x; v[0] = (bf16_t)(t0 > 0.f ? t0 : 0.f);
  float t1 = p0.y + p1.y + bb.y; v[1] = (bf16_t)(t1 > 0.f ? t1 : 0.f);
  float t2 = p0.z + p1.z + bb.z; v[2] = (bf16_t)(t2 > 0.f ? t2 : 0.f);
  float t3 = p0.w + p1.w + bb.w; v[3] = (bf16_t)(t3 > 0.f ? t3 : 0.f);
  *reinterpret_cast<bf16x4*>(h + base) = v;
}

// ---------------- round-8 k_gemm_h (middle fallback): 128x128 counted-vmcnt
__global__ __launch_bounds__(256) void k_gemm_h128(
    const bf16_t* __restrict__ adjb, const bf16_t* __restrict__ xw1t,
    const float* __restrict__ b1, bf16_t* __restrict__ h)
{
  __shared__ bf16_t As[2][128 * 64];
  __shared__ bf16_t Bs[2][128 * 64];
  int d = blockIdx.x;
  int xcd = d & 7;
  int idx = d >> 3;
  int mtile = xcd * 8 + (idx >> 3);
  int ntile = idx & 7;
  int tid = threadIdx.x, lane = tid & 63, wid = tid >> 6;
  int wm = wid >> 1, wn = wid & 1;
  int sl = (lane & 7) ^ (lane >> 3);
  const size_t NN = (size_t)NROWS * NROWS;
  f32x4 acc[4][4] = {};
  const int NT = KTOT / 64;

  auto stage = [&](int buf, int kt) {
    int kk = kt * 64;
    int ord = kk >> 13, mcol = kk & 8191;
    const bf16_t* ao = adjb + (size_t)ord * NN + (size_t)(mtile * 128) * NROWS + mcol;
#pragma unroll
    for (int jj = 0; jj < 4; ++jj) {
      int q = wid * 4 + jj;
      int row = q * 8 + (lane >> 3);
      GLDS(ao + (size_t)row * NROWS + sl * 8, &As[buf][q * 512]);
    }
#pragma unroll
    for (int jj = 0; jj < 4; ++jj) {
      int q = wid * 4 + jj;
      int row = q * 8 + (lane >> 3);
      GLDS(xw1t + (size_t)(ntile * 128 + row) * KTOT + kk + sl * 8, &Bs[buf][q * 512]);
    }
  };
  auto compute = [&](int cur) {
    const bf16_t* Ac = &As[cur][0];
    const bf16_t* Bc = &Bs[cur][0];
#pragma unroll
    for (int ks = 0; ks < 2; ++ks) {
      int psl = ((ks << 2) + (lane >> 4)) ^ (lane & 7);
      bf16x8 a[4], b[4];
      for (int f = 0; f < 4; ++f)
        a[f] = *reinterpret_cast<const bf16x8*>(&Ac[(wm * 64 + f * 16 + (lane & 15)) * 64 + psl * 8]);
      for (int f = 0; f < 4; ++f)
        b[f] = *reinterpret_cast<const bf16x8*>(&Bc[(wn * 64 + f * 16 + (lane & 15)) * 64 + psl * 8]);
      for (int fm = 0; fm < 4; ++fm)
        for (int fn = 0; fn < 4; ++fn)
          acc[fm][fn] = __builtin_amdgcn_mfma_f32_16x16x32_bf16(a[fm], b[fn], acc[fm][fn], 0, 0, 0);
    }
  };

  stage(0, 0);
  for (int t = 0; t < NT - 1; ++t) {
    int cur = t & 1;
    stage(cur ^ 1, t + 1);
    asm volatile("s_waitcnt vmcnt(8)" ::: "memory");
    __builtin_amdgcn_s_barrier();
    compute(cur);
    asm volatile("" ::: "memory");
    __builtin_amdgcn_s_barrier();
  }
  asm volatile("s_waitcnt vmcnt(0)" ::: "memory");
  __builtin_amdgcn_s_barrier();
  compute((NT - 1) & 1);

  for (int fm = 0; fm < 4; ++fm)
    for (int fn = 0; fn < 4; ++fn) {
      int o  = ntile * 128 + wn * 64 + fn * 16 + (lane & 15);
      float bias = b1[o];
      int n0 = mtile * 128 + wm * 64 + fm * 16 + ((lane >> 4) << 2);
      for (int jj = 0; jj < 4; ++jj) {
        float v = acc[fm][fn][jj] + bias;
        v = v > 0.0f ? v : 0.0f;
        h[(size_t)(n0 + jj) * DHID + o] = (bf16_t)v;
      }
    }
}

// ---------------- K3: xw2T[o2][ord*8192+n] = sum_o h(n,o) W2[ord](o,o2)
__global__ __launch_bounds__(256) void k_gemm_xw2(
    const bf16_t* __restrict__ h,     // [8192][1024]
    const bf16_t* __restrict__ w2t,   // [3][64][1024]
    bf16_t* __restrict__ xw2t)        // [64][24576]
{
  __shared__ bf16_t As[128 * 64];
  __shared__ bf16_t Bs[64 * 64];
  int mtile = blockIdx.x, ord = blockIdx.y;
  int tid = threadIdx.x, lane = tid & 63, wid = tid >> 6;
  int wm = wid >> 1, wn = wid & 1;
  int sl = (lane & 7) ^ (lane >> 3);
  f32x4 acc[4][2] = {};
  const bf16_t* w2o = w2t + (size_t)ord * DOUT * DHID;
  for (int kt = 0; kt < DHID; kt += 64) {
    for (int j = 0; j < 4; ++j) {           // A: h rows
      int q = wid * 4 + j;
      int row = q * 8 + (lane >> 3);
      GLDS(h + (size_t)(mtile * 128 + row) * DHID + kt + sl * 8, &As[q * 512]);
    }
    for (int j = 0; j < 2; ++j) {           // B: W2T rows (o2), 8 KB
      int q = wid * 2 + j;
      int row = q * 8 + (lane >> 3);
      GLDS(w2o + (size_t)row * DHID + kt + sl * 8, &Bs[q * 512]);
    }
    __syncthreads();
    for (int ks = 0; ks < 2; ++ks) {
      int psl = ((ks << 2) + (lane >> 4)) ^ (lane & 7);
      bf16x8 a[4], b[2];
      for (int f = 0; f < 4; ++f)
        a[f] = *reinterpret_cast<const bf16x8*>(&As[(wm * 64 + f * 16 + (lane & 15)) * 64 + psl * 8]);
      for (int f = 0; f < 2; ++f)
        b[f] = *reinterpret_cast<const bf16x8*>(&Bs[(wn * 32 + f * 16 + (lane & 15)) * 64 + psl * 8]);
      for (int fm = 0; fm < 4; ++fm)
        for (int fn = 0; fn < 2; ++fn)
          acc[fm][fn] = __builtin_amdgcn_mfma_f32_16x16x32_bf16(a[fm], b[fn], acc[fm][fn], 0, 0, 0);
    }
    __syncthreads();
  }
  for (int fm = 0; fm < 4; ++fm)
    for (int fn = 0; fn < 2; ++fn) {
      int o2 = wn * 32 + fn * 16 + (lane & 15);
      int n0 = mtile * 128 + wm * 64 + fm * 16 + ((lane >> 4) << 2);
      bf16x4 v;
      v[0] = (bf16_t)acc[fm][fn][0]; v[1] = (bf16_t)acc[fm][fn][1];
      v[2] = (bf16_t)acc[fm][fn][2]; v[3] = (bf16_t)acc[fm][fn][3];
      *reinterpret_cast<bf16x4*>(&xw2t[(size_t)o2 * KTOT + ord * NROWS + n0]) = v;
    }
}

// ---------------- K4a: partial z = adjcat @ xw2, K split 16, single-buffer
__global__ __launch_bounds__(256) void k_gemm_out(
    const bf16_t* __restrict__ adjb,
    const bf16_t* __restrict__ xw2t,   // [64][24576]
    float* __restrict__ part)          // [16][8192][64]
{
  __shared__ bf16_t As[128 * 64];
  __shared__ bf16_t Bs[64 * 64];
  int mtile = blockIdx.x, ksp = blockIdx.y;
  int tid = threadIdx.x, lane = tid & 63, wid = tid >> 6;
  int wm = wid >> 1, wn = wid & 1;
  int sl = (lane & 7) ^ (lane >> 3);
  const size_t NN = (size_t)NROWS * NROWS;
  f32x4 acc[4][2] = {};
  for (int kt = ksp * 24; kt < ksp * 24 + 24; ++kt) {
    int kk = kt * 64;
    int ord = kk >> 13, mcol = kk & 8191;
    const bf16_t* ao = adjb + (size_t)ord * NN + (size_t)(mtile * 128) * NROWS + mcol;
    for (int j = 0; j < 4; ++j) {           // A: adj_bf rows
      int q = wid * 4 + j;
      int row = q * 8 + (lane >> 3);
      GLDS(ao + (size_t)row * NROWS + sl * 8, &As[q * 512]);
    }
    for (int j = 0; j < 2; ++j) {           // B: xw2T rows (o2)
      int q = wid * 2 + j;
      int row = q * 8 + (lane >> 3);
      GLDS(xw2t + (size_t)row * KTOT + kk + sl * 8, &Bs[q * 512]);
    }
    __syncthreads();
    for (int ks = 0; ks < 2; ++ks) {
      int psl = ((ks << 2) + (lane >> 4)) ^ (lane & 7);
      bf16x8 a[4], b[2];
      for (int f = 0; f < 4; ++f)
        a[f] = *reinterpret_cast<const bf16x8*>(&As[(wm * 64 + f * 16 + (lane & 15)) * 64 + psl * 8]);
      for (int f = 0; f < 2; ++f)
        b[f] = *reinterpret_cast<const bf16x8*>(&Bs[(wn * 32 + f * 16 + (lane & 15)) * 64 + psl * 8]);
      for (int fm = 0; fm < 4; ++fm)
        for (int fn = 0; fn < 2; ++fn)
          acc[fm][fn] = __builtin_amdgcn_mfma_f32_16x16x32_bf16(a[fm], b[fn], acc[fm][fn], 0, 0, 0);
    }
    __syncthreads();
  }
  float* pout = part + (size_t)ksp * NROWS * DOUT;
  for (int fm = 0; fm < 4; ++fm)
    for (int fn = 0; fn < 2; ++fn) {
      int o2 = wn * 32 + fn * 16 + (lane & 15);
      int n0 = mtile * 128 + wm * 64 + fm * 16 + ((lane >> 4) << 2);
      for (int j = 0; j < 4; ++j)
        pout[(size_t)(n0 + j) * DOUT + o2] = acc[fm][fn][j];
    }
}

// ---------------- K4b: sum 16 partials + b2, row log_softmax ----------------
__global__ void k_logsoftmax(const float* __restrict__ part, const float* __restrict__ b2,
                             float* __restrict__ out) {
  int wid = threadIdx.x >> 6, lane = threadIdx.x & 63;
  int n = blockIdx.x * 4 + wid;
  size_t s = (size_t)NROWS * DOUT;
  float v = b2[lane];
#pragma unroll
  for (int p = 0; p < 16; ++p)
    v += part[(size_t)p * s + (size_t)n * DOUT + lane];
  float mx = v;
  for (int d = 32; d; d >>= 1) mx = fmaxf(mx, __shfl_xor(mx, d));
  float e = expf(v - mx);
  float sum = e;
  for (int d = 32; d; d >>= 1) sum += __shfl_xor(sum, d);
  out[(size_t)n * DOUT + lane] = (v - mx) - logf(sum);
}

// ================= fallback (small ws): f32-staged kernels =================
__global__ __launch_bounds__(256) void k_gemm_h_f32(
    const float* __restrict__ adj, const bf16_t* __restrict__ xw1t,
    const float* __restrict__ b1, bf16_t* __restrict__ h)
{
  __shared__ bf16_t As[128 * 64];
  __shared__ bf16_t Bs[128 * 64];
  int d = blockIdx.x;
  int xcd = d & 7, idx = d >> 3;
  int mtile = xcd * 8 + (idx >> 3), ntile = idx & 7;
  int tid = threadIdx.x, lane = tid & 63, wid = tid >> 6;
  int wm = wid >> 1, wn = wid & 1;
  int sl = (lane & 7) ^ (lane >> 3);
  f32x4 acc[4][4] = {};
  for (int kt = 0; kt < KTOT / 64; ++kt) {
    int kk0 = kt * 64;
    int ord = kk0 >> 13, mcol = kk0 & 8191;
    for (int j = 0; j < 4; ++j) {
      int q = wid * 4 + j;
      int row = q * 8 + (lane >> 3);
      GLDS(xw1t + (size_t)(ntile * 128 + row) * KTOT + kk0 + sl * 8, &Bs[q * 512]);
    }
    const float* abase = adj + (size_t)ord * NROWS * NROWS + (size_t)(mtile * 128) * NROWS + mcol;
    bf16x8 st[4]; int mrow[4], kb[4];
    for (int i = 0; i < 4; ++i) {
      int c = i * 256 + tid;
      mrow[i] = c >> 3; kb[i] = c & 7;
      const float4* p = reinterpret_cast<const float4*>(abase + (size_t)mrow[i] * NROWS + kb[i] * 8);
      float4 v0 = p[0], v1 = p[1];
      bf16x8 o;
      o[0]=(bf16_t)v0.x; o[1]=(bf16_t)v0.y; o[2]=(bf16_t)v0.z; o[3]=(bf16_t)v0.w;
      o[4]=(bf16_t)v1.x; o[5]=(bf16_t)v1.y; o[6]=(bf16_t)v1.z; o[7]=(bf16_t)v1.w;
      st[i] = o;
    }
    for (int i = 0; i < 4; ++i)
      *reinterpret_cast<bf16x8*>(&As[mrow[i] * 64 + (kb[i] ^ (mrow[i] & 7)) * 8]) = st[i];
    __syncthreads();
    for (int ks = 0; ks < 2; ++ks) {
      int psl = ((ks << 2) + (lane >> 4)) ^ (lane & 7);
      bf16x8 a[4], b[4];
      for (int f = 0; f < 4; ++f)
        a[f] = *reinterpret_cast<const bf16x8*>(&As[(wm * 64 + f * 16 + (lane & 15)) * 64 + psl * 8]);
      for (int f = 0; f < 4; ++f)
        b[f] = *reinterpret_cast<const bf16x8*>(&Bs[(wn * 64 + f * 16 + (lane & 15)) * 64 + psl * 8]);
      for (int fm = 0; fm < 4; ++fm)
        for (int fn = 0; fn < 4; ++fn)
          acc[fm][fn] = __builtin_amdgcn_mfma_f32_16x16x32_bf16(a[fm], b[fn], acc[fm][fn], 0, 0, 0);
    }
    __syncthreads();
  }
  for (int fm = 0; fm < 4; ++fm)
    for (int fn = 0; fn < 4; ++fn) {
      int o  = ntile * 128 + wn * 64 + fn * 16 + (lane & 15);
      float bias = b1[o];
      int n0 = mtile * 128 + wm * 64 + fm * 16 + ((lane >> 4) << 2);
      for (int j = 0; j < 4; ++j) {
        float v = acc[fm][fn][j] + bias;
        v = v > 0.0f ? v : 0.0f;
        h[(size_t)(n0 + j) * DHID + o] = (bf16_t)v;
      }
    }
}

__global__ __launch_bounds__(256) void k_gemm_out_f32(
    const float* __restrict__ adj, const bf16_t* __restrict__ xw2t,
    float* __restrict__ part)          // [16][8192][64]
{
  __shared__ bf16_t As[128 * 64];
  __shared__ bf16_t Bs[64 * 64];
  int mtile = blockIdx.x, ksp = blockIdx.y;
  int tid = threadIdx.x, lane = tid & 63, wid = tid >> 6;
  int wm = wid >> 1, wn = wid & 1;
  int sl = (lane & 7) ^ (lane >> 3);
  f32x4 acc[4][2] = {};
  for (int kt = ksp * 24; kt < ksp * 24 + 24; ++kt) {
    int kk0 = kt * 64;
    int ord = kk0 >> 13, mcol = kk0 & 8191;
    for (int j = 0; j < 2; ++j) {
      int q = wid * 2 + j;
      int row = q * 8 + (lane >> 3);
      GLDS(xw2t + (size_t)row * KTOT + kk0 + sl * 8, &Bs[q * 512]);
    }
    const float* abase = adj + (size_t)ord * NROWS * NROWS + (size_t)(mtile * 128) * NROWS + mcol;
    bf16x8 st[4]; int mrow[4], kb[4];
    for (int i = 0; i < 4; ++i) {
      int c = i * 256 + tid;
      mrow[i] = c >> 3; kb[i] = c & 7;
      const float4* p = reinterpret_cast<const float4*>(abase + (size_t)mrow[i] * NROWS + kb[i] * 8);
      float4 v0 = p[0], v1 = p[1];
      bf16x8 o;
      o[0]=(bf16_t)v0.x; o[1]=(bf16_t)v0.y; o[2]=(bf16_t)v0.z; o[3]=(bf16_t)v0.w;
      o[4]=(bf16_t)v1.x; o[5]=(bf16_t)v1.y; o[6]=(bf16_t)v1.z; o[7]=(bf16_t)v1.w;
      st[i] = o;
    }
    for (int i = 0; i < 4; ++i)
      *reinterpret_cast<bf16x8*>(&As[mrow[i] * 64 + (kb[i] ^ (mrow[i] & 7)) * 8]) = st[i];
    __syncthreads();
    for (int ks = 0; ks < 2; ++ks) {
      int psl = ((ks << 2) + (lane >> 4)) ^ (lane & 7);
      bf16x8 a[4], b[2];
      for (int f = 0; f < 4; ++f)
        a[f] = *reinterpret_cast<const bf16x8*>(&As[(wm * 64 + f * 16 + (lane & 15)) * 64 + psl * 8]);
      for (int f = 0; f < 2; ++f)
        b[f] = *reinterpret_cast<const bf16x8*>(&Bs[(wn * 32 + f * 16 + (lane & 15)) * 64 + psl * 8]);
      for (int fm = 0; fm < 4; ++fm)
        for (int fn = 0; fn < 2; ++fn)
          acc[fm][fn] = __builtin_amdgcn_mfma_f32_16x16x32_bf16(a[fm], b[fn], acc[fm][fn], 0, 0, 0);
    }
    __syncthreads();
  }
  float* pout = part + (size_t)ksp * NROWS * DOUT;
  for (int fm = 0; fm < 4; ++fm)
    for (int fn = 0; fn < 2; ++fn) {
      int o2 = wn * 32 + fn * 16 + (lane & 15);
      int n0 = mtile * 128 + wm * 64 + fm * 16 + ((lane >> 4) << 2);
      for (int j = 0; j < 4; ++j)
        pout[(size_t)(n0 + j) * DOUT + o2] = acc[fm][fn][j];
    }
}

// ---------------------------------------------------------------------------
extern "C" void kernel_launch(void* const* d_in, const int* in_sizes, int n_in,
                              void* d_out, int out_size, void* d_ws, size_t ws_size,
                              hipStream_t stream) {
  const float* x   = (const float*)d_in[0];
  const float* adj = (const float*)d_in[1];
  const float* W1  = (const float*)d_in[2];
  const float* b1  = (const float*)d_in[3];
  const float* W2  = (const float*)d_in[4];
  const float* b2  = (const float*)d_in[5];
  float* out = (float*)d_out;
  char* ws = (char*)d_ws;

  const size_t ADJB_SZ  = 402653184ULL;   // 3*8192*8192*2
  const size_t NEED_OLD = 484835328ULL;   // round-8 layout
  const size_t NEED_NEW = 551944192ULL;   // + 64 MB hpart

  if (ws_size >= NEED_OLD) {
    bf16_t* adjb = (bf16_t*)(ws + 0);                  // 384 MB
    bf16_t* xb   = (bf16_t*)(ws + ADJB_SZ);            //   8 MB
    bf16_t* w1t  = (bf16_t*)(ws + ADJB_SZ + 8388608);  //   3 MB
    bf16_t* w2t  = (bf16_t*)(ws + ADJB_SZ + 11534336); // 384 KB
    bf16_t* xw1t = (bf16_t*)(ws + ADJB_SZ + 11927552); //  48 MB
    bf16_t* h    = (bf16_t*)(ws + ADJB_SZ + 62259200); //  16 MB
    bf16_t* xw2t = (bf16_t*)(ws + ADJB_SZ + 79036416); //   3 MB
    float*  hpart = (float*)(ws + ADJB_SZ + 82182144); //  64 MB (new path only)
    // gemm_out partials: alias hpart (new) or xw1t (old) -- both dead by then
    float*  part = (ws_size >= NEED_NEW) ? hpart
                                         : (float*)(ws + ADJB_SZ + 11927552);

    k_cvt_adj<<<2048, 256, 0, stream>>>(adj, adjb);
    k_cvt_x<<<2048, 256, 0, stream>>>(x, xb);
    k_transpose_cvt<<<dim3(16, 8, 3), 256, 0, stream>>>(W1, w1t, DIN, DHID);
    k_transpose_cvt<<<dim3(1, 16, 3), 256, 0, stream>>>(W2, w2t, DHID, DOUT);
    k_gemm_xw1<<<dim3(8, 64, 3), 256, 0, stream>>>(xb, w1t, xw1t);
    if (ws_size >= NEED_NEW) {
      k_gemm_h256<<<256, 512, 0, stream>>>(adjb, xw1t, hpart);
      k_reduce_h<<<8192, 256, 0, stream>>>(hpart, b1, h);
    } else {
      k_gemm_h128<<<512, 256, 0, stream>>>(adjb, xw1t, b1, h);
    }
    k_gemm_xw2<<<dim3(64, 3), 256, 0, stream>>>(h, w2t, xw2t);
    k_gemm_out<<<dim3(64, 16), 256, 0, stream>>>(adjb, xw2t, part);
    k_logsoftmax<<<2048, 256, 0, stream>>>(part, b2, out);
  } else {
    bf16_t* xb   = (bf16_t*)(ws + 0);
    bf16_t* w1t  = (bf16_t*)(ws + 8388608);
    bf16_t* w2t  = (bf16_t*)(ws + 11534336);
    bf16_t* xw1t = (bf16_t*)(ws + 11927552);
    bf16_t* h    = (bf16_t*)(ws + 62259200);
    bf16_t* xw2t = (bf16_t*)(ws + 79036416);
    float*  part = (float*)(ws + 11927552);

    k_cvt_x<<<2048, 256, 0, stream>>>(x, xb);
    k_transpose_cvt<<<dim3(16, 8, 3), 256, 0, stream>>>(W1, w1t, DIN, DHID);
    k_transpose_cvt<<<dim3(1, 16, 3), 256, 0, stream>>>(W2, w2t, DHID, DOUT);
    k_gemm_xw1<<<dim3(8, 64, 3), 256, 0, stream>>>(xb, w1t, xw1t);
    k_gemm_h_f32<<<512, 256, 0, stream>>>(adj, xw1t, b1, h);
    k_gemm_xw2<<<dim3(64, 3), 256, 0, stream>>>(h, w2t, xw2t);
    k_gemm_out_f32<<<dim3(64, 16), 256, 0, stream>>>(adj, xw2t, part);
    k_logsoftmax<<<2048, 256, 0, stream>>>(part, b2, out);
  }
}

// Round 10
// 888.941 us; speedup vs baseline: 1.0688x; 1.0688x over previous
//
#include <hip/hip_runtime.h>
#include <hip/hip_bf16.h>
#include <cstdint>
#include <cstddef>

// ---------------------------------------------------------------------------
// MultiValGCN: out = log_softmax( adjcat @ relu(adjcat @ (x W1)cat + b1) W2cat + b2 )
// Round 10: k_gemm_h256 (256x256, 8 waves) + counted-vmcnt double-buffer.
// Regime argument: compute phase ~2500cy > load latency ~900cy, so 1-deep
// prefetch now hides staging (it couldn't at 128^2 where compute ~620cy).
// Same proven vmcnt(8)/raw-barrier pattern as rounds 7/8. LDS 128 KB.
// ---------------------------------------------------------------------------

typedef __bf16 bf16_t;
typedef __bf16 bf16x8 __attribute__((ext_vector_type(8)));
typedef __bf16 bf16x4 __attribute__((ext_vector_type(4)));
typedef float  f32x4  __attribute__((ext_vector_type(4)));

#define NROWS 8192
#define DIN   512
#define DHID  1024
#define DOUT  64
#define ORD   3
#define KTOT  24576   // ORD*NROWS

#define GLDS(g, l) __builtin_amdgcn_global_load_lds( \
    (__attribute__((address_space(1))) void*)(g),    \
    (__attribute__((address_space(3))) void*)(l), 16, 0, 0)

// LDS tile layout: [rows][8 slots of 8 bf16]; physical slot = logical ^ (row&7).
// GLDS writes linearly, so the GLOBAL source reads slot (lane&7)^(lane>>3).

// ---------------- x: f32 -> bf16 ----------------
__global__ void k_cvt_x(const float* __restrict__ x, bf16_t* __restrict__ xb) {
  int i = blockIdx.x * blockDim.x + threadIdx.x;            // one per 8 elems
  const float4* p = reinterpret_cast<const float4*>(x) + (size_t)i * 2;
  float4 v0 = p[0], v1 = p[1];
  bf16x8 o;
  o[0]=(bf16_t)v0.x; o[1]=(bf16_t)v0.y; o[2]=(bf16_t)v0.z; o[3]=(bf16_t)v0.w;
  o[4]=(bf16_t)v1.x; o[5]=(bf16_t)v1.y; o[6]=(bf16_t)v1.z; o[7]=(bf16_t)v1.w;
  *reinterpret_cast<bf16x8*>(xb + (size_t)i * 8) = o;
}

// ---------------- adj: f32 -> bf16, full 192M-element stream ----------------
__global__ void k_cvt_adj(const float* __restrict__ a, bf16_t* __restrict__ ab) {
  size_t i = (size_t)blockIdx.x * blockDim.x + threadIdx.x;  // one per 8 elems
  const size_t stride = (size_t)gridDim.x * blockDim.x;
  const float4* src = reinterpret_cast<const float4*>(a);
#pragma unroll 4
  for (int it = 0; it < 48; ++it, i += stride) {
    float4 v0 = src[i * 2], v1 = src[i * 2 + 1];
    bf16x8 o;
    o[0]=(bf16_t)v0.x; o[1]=(bf16_t)v0.y; o[2]=(bf16_t)v0.z; o[3]=(bf16_t)v0.w;
    o[4]=(bf16_t)v1.x; o[5]=(bf16_t)v1.y; o[6]=(bf16_t)v1.z; o[7]=(bf16_t)v1.w;
    *reinterpret_cast<bf16x8*>(ab + i * 8) = o;
  }
}

// ---------------- W transpose + cvt: src f32 [R][C] -> dst bf16 [C][R], per order z
__global__ void k_transpose_cvt(const float* __restrict__ src, bf16_t* __restrict__ dst,
                                int R, int C) {
  __shared__ float tile[64][65];
  int ord = blockIdx.z;
  src += (size_t)ord * R * C;
  dst += (size_t)ord * R * C;
  int c0 = blockIdx.x * 64, r0 = blockIdx.y * 64;
  for (int i = 0; i < 16; ++i) {
    int idx = i * 256 + threadIdx.x;
    int r = idx >> 6, c = idx & 63;
    tile[r][c] = src[(size_t)(r0 + r) * C + c0 + c];
  }
  __syncthreads();
  for (int i = 0; i < 16; ++i) {
    int idx = i * 256 + threadIdx.x;
    int cc = idx >> 6, rr = idx & 63;
    dst[(size_t)(c0 + cc) * R + r0 + rr] = (bf16_t)tile[rr][cc];
  }
}

// ---------------- K1: xw1T[o][ord*8192+n] = sum_i x(n,i) W1[ord](i,o)  (bf16)
__global__ __launch_bounds__(256) void k_gemm_xw1(
    const bf16_t* __restrict__ xb,    // [8192][512]
    const bf16_t* __restrict__ w1t,   // [3][1024][512]
    bf16_t* __restrict__ xw1t)        // [1024][24576]
{
  __shared__ bf16_t As[128 * 64];
  __shared__ bf16_t Bs[128 * 64];
  int ntile = blockIdx.x, mtile = blockIdx.y, ord = blockIdx.z;
  int tid = threadIdx.x, lane = tid & 63, wid = tid >> 6;
  int wm = wid >> 1, wn = wid & 1;
  int sl = (lane & 7) ^ (lane >> 3);              // pre-swizzled source slot
  f32x4 acc[4][4] = {};
  const bf16_t* w1o = w1t + (size_t)ord * DHID * DIN;
  for (int kt = 0; kt < DIN; kt += 64) {
    for (int j = 0; j < 4; ++j) {           // A: x rows, 16 KB
      int q = wid * 4 + j;
      int row = q * 8 + (lane >> 3);
      GLDS(xb + (size_t)(mtile * 128 + row) * DIN + kt + sl * 8, &As[q * 512]);
    }
    for (int j = 0; j < 4; ++j) {           // B: W1T rows (o), 16 KB
      int q = wid * 4 + j;
      int row = q * 8 + (lane >> 3);
      GLDS(w1o + (size_t)(ntile * 128 + row) * DIN + kt + sl * 8, &Bs[q * 512]);
    }
    __syncthreads();
    for (int ks = 0; ks < 2; ++ks) {
      int psl = ((ks << 2) + (lane >> 4)) ^ (lane & 7);
      bf16x8 a[4], b[4];
      for (int f = 0; f < 4; ++f)
        a[f] = *reinterpret_cast<const bf16x8*>(&As[(wm * 64 + f * 16 + (lane & 15)) * 64 + psl * 8]);
      for (int f = 0; f < 4; ++f)
        b[f] = *reinterpret_cast<const bf16x8*>(&Bs[(wn * 64 + f * 16 + (lane & 15)) * 64 + psl * 8]);
      for (int fm = 0; fm < 4; ++fm)
        for (int fn = 0; fn < 4; ++fn)
          acc[fm][fn] = __builtin_amdgcn_mfma_f32_16x16x32_bf16(a[fm], b[fn], acc[fm][fn], 0, 0, 0);
    }
    __syncthreads();
  }
  for (int fm = 0; fm < 4; ++fm)
    for (int fn = 0; fn < 4; ++fn) {
      int o  = ntile * 128 + wn * 64 + fn * 16 + (lane & 15);
      int n0 = mtile * 128 + wm * 64 + fm * 16 + ((lane >> 4) << 2);
      bf16x4 v;
      v[0] = (bf16_t)acc[fm][fn][0]; v[1] = (bf16_t)acc[fm][fn][1];
      v[2] = (bf16_t)acc[fm][fn][2]; v[3] = (bf16_t)acc[fm][fn][3];
      *reinterpret_cast<bf16x4*>(&xw1t[(size_t)o * KTOT + ord * NROWS + n0]) = v;
    }
}

// ---------------- K2: hpart[ksp] = adj[ksp-half] @ xw1. 256x256, 8 waves,
// counted-vmcnt double-buffer (vmcnt(8): tile t landed, tile t+1 in flight).
__global__ __launch_bounds__(512) void k_gemm_h256(
    const bf16_t* __restrict__ adjb,   // [3][8192][8192] bf16
    const bf16_t* __restrict__ xw1t,   // [1024][24576]
    float* __restrict__ hpart)         // [2][8192][1024] f32
{
  __shared__ bf16_t As[2][256 * 64];   // 64 KB
  __shared__ bf16_t Bs[2][256 * 64];   // 64 KB
  int d = blockIdx.x;               // 0..255
  int xcd = d & 7;
  int s = d >> 3;                   // 0..31
  int ksp = xcd & 1;
  int mtile = (xcd >> 1) * 8 + (s >> 2);   // 0..31
  int ntile = s & 3;                       // 0..3
  int tid = threadIdx.x, lane = tid & 63, wid = tid >> 6;   // wid 0..7
  int wm = wid >> 2, wn = wid & 3;         // 2M x 4N, per-wave 128x64
  int sl = (lane & 7) ^ (lane >> 3);
  const size_t NN = (size_t)NROWS * NROWS;
  f32x4 acc[8][4] = {};
  const int T0 = ksp * 192, NT = 192;

  // 8 GLDS per wave per stage (4 A + 4 B) -> vmcnt granularity.
  auto stage = [&](int buf, int t) {
    int kk = (T0 + t) * 64;
    int ord = kk >> 13, mcol = kk & 8191;
    const bf16_t* ao = adjb + (size_t)ord * NN + (size_t)(mtile * 256) * NROWS + mcol;
#pragma unroll
    for (int j = 0; j < 4; ++j) {           // A: 256 adj rows, 32 KB
      int q = wid * 4 + j;
      int row = q * 8 + (lane >> 3);
      GLDS(ao + (size_t)row * NROWS + sl * 8, &As[buf][q * 512]);
    }
#pragma unroll
    for (int j = 0; j < 4; ++j) {           // B: 256 xw1T rows (o), 32 KB
      int q = wid * 4 + j;
      int row = q * 8 + (lane >> 3);
      GLDS(xw1t + (size_t)(ntile * 256 + row) * KTOT + kk + sl * 8, &Bs[buf][q * 512]);
    }
  };

  auto compute = [&](int cur) {
    const bf16_t* Ac = &As[cur][0];
    const bf16_t* Bc = &Bs[cur][0];
#pragma unroll
    for (int ks = 0; ks < 2; ++ks) {
      int psl = ((ks << 2) + (lane >> 4)) ^ (lane & 7);
      bf16x8 a[8], b[4];
#pragma unroll
      for (int f = 0; f < 8; ++f)
        a[f] = *reinterpret_cast<const bf16x8*>(&Ac[(wm * 128 + f * 16 + (lane & 15)) * 64 + psl * 8]);
#pragma unroll
      for (int f = 0; f < 4; ++f)
        b[f] = *reinterpret_cast<const bf16x8*>(&Bc[(wn * 64 + f * 16 + (lane & 15)) * 64 + psl * 8]);
#pragma unroll
      for (int fm = 0; fm < 8; ++fm)
#pragma unroll
        for (int fn = 0; fn < 4; ++fn)
          acc[fm][fn] = __builtin_amdgcn_mfma_f32_16x16x32_bf16(a[fm], b[fn], acc[fm][fn], 0, 0, 0);
    }
  };

  stage(0, 0);                               // tile 0: 8 loads in flight
  for (int t = 0; t < NT - 1; ++t) {
    int cur = t & 1;
    stage(cur ^ 1, t + 1);                   // +8 loads, stay in flight
    // FIFO: oldest 8 (tile t) drain; tile t+1's 8 keep flying under compute.
    asm volatile("s_waitcnt vmcnt(8)" ::: "memory");
    __builtin_amdgcn_s_barrier();            // all waves' tile-t data landed
    compute(cur);
    asm volatile("" ::: "memory");
    __builtin_amdgcn_s_barrier();            // all readers of buf[cur] done
  }
  asm volatile("s_waitcnt vmcnt(0)" ::: "memory");
  __builtin_amdgcn_s_barrier();
  compute((NT - 1) & 1);

  float* pout = hpart + (size_t)ksp * NROWS * DHID;
#pragma unroll
  for (int fm = 0; fm < 8; ++fm)
#pragma unroll
    for (int fn = 0; fn < 4; ++fn) {
      int o  = ntile * 256 + wn * 64 + fn * 16 + (lane & 15);
      int n0 = mtile * 256 + wm * 128 + fm * 16 + ((lane >> 4) << 2);
      for (int j = 0; j < 4; ++j)
        pout[(size_t)(n0 + j) * DHID + o] = acc[fm][fn][j];
    }
}

// ---------------- reduce: h = relu(hpart0 + hpart1 + b1), bf16 ----------------
__global__ void k_reduce_h(const float* __restrict__ hpart, const float* __restrict__ b1,
                           bf16_t* __restrict__ h) {
  size_t i4 = (size_t)blockIdx.x * blockDim.x + threadIdx.x;   // one per 4 elems
  size_t base = i4 * 4;
  int col = (int)(base & (DHID - 1));
  const size_t S = (size_t)NROWS * DHID;
  float4 p0 = *reinterpret_cast<const float4*>(hpart + base);
  float4 p1 = *reinterpret_cast<const float4*>(hpart + S + base);
  float4 bb = *reinterpret_cast<const float4*>(b1 + col);
  bf16x4 v;
  float t0 = p0.x + p1.x + bb.x; v[0] = (bf16_t)(t0 > 0.f ? t0 : 0.f);
  float t1 = p0.y + p1.y + bb.y; v[1] = (bf16_t)(t1 > 0.f ? t1 : 0.f);
  float t2 = p0.z + p1.z + bb.z; v[2] = (bf16_t)(t2 > 0.f ? t2 : 0.f);
  float t3 = p0.w + p1.w + bb.w; v[3] = (bf16_t)(t3 > 0.f ? t3 : 0.f);
  *reinterpret_cast<bf16x4*>(h + base) = v;
}

// ---------------- round-8 k_gemm_h (middle fallback): 128x128 counted-vmcnt
__global__ __launch_bounds__(256) void k_gemm_h128(
    const bf16_t* __restrict__ adjb, const bf16_t* __restrict__ xw1t,
    const float* __restrict__ b1, bf16_t* __restrict__ h)
{
  __shared__ bf16_t As[2][128 * 64];
  __shared__ bf16_t Bs[2][128 * 64];
  int d = blockIdx.x;
  int xcd = d & 7;
  int idx = d >> 3;
  int mtile = xcd * 8 + (idx >> 3);
  int ntile = idx & 7;
  int tid = threadIdx.x, lane = tid & 63, wid = tid >> 6;
  int wm = wid >> 1, wn = wid & 1;
  int sl = (lane & 7) ^ (lane >> 3);
  const size_t NN = (size_t)NROWS * NROWS;
  f32x4 acc[4][4] = {};
  const int NT = KTOT / 64;

  auto stage = [&](int buf, int kt) {
    int kk = kt * 64;
    int ord = kk >> 13, mcol = kk & 8191;
    const bf16_t* ao = adjb + (size_t)ord * NN + (size_t)(mtile * 128) * NROWS + mcol;
#pragma unroll
    for (int jj = 0; jj < 4; ++jj) {
      int q = wid * 4 + jj;
      int row = q * 8 + (lane >> 3);
      GLDS(ao + (size_t)row * NROWS + sl * 8, &As[buf][q * 512]);
    }
#pragma unroll
    for (int jj = 0; jj < 4; ++jj) {
      int q = wid * 4 + jj;
      int row = q * 8 + (lane >> 3);
      GLDS(xw1t + (size_t)(ntile * 128 + row) * KTOT + kk + sl * 8, &Bs[buf][q * 512]);
    }
  };
  auto compute = [&](int cur) {
    const bf16_t* Ac = &As[cur][0];
    const bf16_t* Bc = &Bs[cur][0];
#pragma unroll
    for (int ks = 0; ks < 2; ++ks) {
      int psl = ((ks << 2) + (lane >> 4)) ^ (lane & 7);
      bf16x8 a[4], b[4];
      for (int f = 0; f < 4; ++f)
        a[f] = *reinterpret_cast<const bf16x8*>(&Ac[(wm * 64 + f * 16 + (lane & 15)) * 64 + psl * 8]);
      for (int f = 0; f < 4; ++f)
        b[f] = *reinterpret_cast<const bf16x8*>(&Bc[(wn * 64 + f * 16 + (lane & 15)) * 64 + psl * 8]);
      for (int fm = 0; fm < 4; ++fm)
        for (int fn = 0; fn < 4; ++fn)
          acc[fm][fn] = __builtin_amdgcn_mfma_f32_16x16x32_bf16(a[fm], b[fn], acc[fm][fn], 0, 0, 0);
    }
  };

  stage(0, 0);
  for (int t = 0; t < NT - 1; ++t) {
    int cur = t & 1;
    stage(cur ^ 1, t + 1);
    asm volatile("s_waitcnt vmcnt(8)" ::: "memory");
    __builtin_amdgcn_s_barrier();
    compute(cur);
    asm volatile("" ::: "memory");
    __builtin_amdgcn_s_barrier();
  }
  asm volatile("s_waitcnt vmcnt(0)" ::: "memory");
  __builtin_amdgcn_s_barrier();
  compute((NT - 1) & 1);

  for (int fm = 0; fm < 4; ++fm)
    for (int fn = 0; fn < 4; ++fn) {
      int o  = ntile * 128 + wn * 64 + fn * 16 + (lane & 15);
      float bias = b1[o];
      int n0 = mtile * 128 + wm * 64 + fm * 16 + ((lane >> 4) << 2);
      for (int jj = 0; jj < 4; ++jj) {
        float v = acc[fm][fn][jj] + bias;
        v = v > 0.0f ? v : 0.0f;
        h[(size_t)(n0 + jj) * DHID + o] = (bf16_t)v;
      }
    }
}

// ---------------- K3: xw2T[o2][ord*8192+n] = sum_o h(n,o) W2[ord](o,o2)
__global__ __launch_bounds__(256) void k_gemm_xw2(
    const bf16_t* __restrict__ h,     // [8192][1024]
    const bf16_t* __restrict__ w2t,   // [3][64][1024]
    bf16_t* __restrict__ xw2t)        // [64][24576]
{
  __shared__ bf16_t As[128 * 64];
  __shared__ bf16_t Bs[64 * 64];
  int mtile = blockIdx.x, ord = blockIdx.y;
  int tid = threadIdx.x, lane = tid & 63, wid = tid >> 6;
  int wm = wid >> 1, wn = wid & 1;
  int sl = (lane & 7) ^ (lane >> 3);
  f32x4 acc[4][2] = {};
  const bf16_t* w2o = w2t + (size_t)ord * DOUT * DHID;
  for (int kt = 0; kt < DHID; kt += 64) {
    for (int j = 0; j < 4; ++j) {           // A: h rows
      int q = wid * 4 + j;
      int row = q * 8 + (lane >> 3);
      GLDS(h + (size_t)(mtile * 128 + row) * DHID + kt + sl * 8, &As[q * 512]);
    }
    for (int j = 0; j < 2; ++j) {           // B: W2T rows (o2), 8 KB
      int q = wid * 2 + j;
      int row = q * 8 + (lane >> 3);
      GLDS(w2o + (size_t)row * DHID + kt + sl * 8, &Bs[q * 512]);
    }
    __syncthreads();
    for (int ks = 0; ks < 2; ++ks) {
      int psl = ((ks << 2) + (lane >> 4)) ^ (lane & 7);
      bf16x8 a[4], b[2];
      for (int f = 0; f < 4; ++f)
        a[f] = *reinterpret_cast<const bf16x8*>(&As[(wm * 64 + f * 16 + (lane & 15)) * 64 + psl * 8]);
      for (int f = 0; f < 2; ++f)
        b[f] = *reinterpret_cast<const bf16x8*>(&Bs[(wn * 32 + f * 16 + (lane & 15)) * 64 + psl * 8]);
      for (int fm = 0; fm < 4; ++fm)
        for (int fn = 0; fn < 2; ++fn)
          acc[fm][fn] = __builtin_amdgcn_mfma_f32_16x16x32_bf16(a[fm], b[fn], acc[fm][fn], 0, 0, 0);
    }
    __syncthreads();
  }
  for (int fm = 0; fm < 4; ++fm)
    for (int fn = 0; fn < 2; ++fn) {
      int o2 = wn * 32 + fn * 16 + (lane & 15);
      int n0 = mtile * 128 + wm * 64 + fm * 16 + ((lane >> 4) << 2);
      bf16x4 v;
      v[0] = (bf16_t)acc[fm][fn][0]; v[1] = (bf16_t)acc[fm][fn][1];
      v[2] = (bf16_t)acc[fm][fn][2]; v[3] = (bf16_t)acc[fm][fn][3];
      *reinterpret_cast<bf16x4*>(&xw2t[(size_t)o2 * KTOT + ord * NROWS + n0]) = v;
    }
}

// ---------------- K4a: partial z = adjcat @ xw2, K split 16, single-buffer
__global__ __launch_bounds__(256) void k_gemm_out(
    const bf16_t* __restrict__ adjb,
    const bf16_t* __restrict__ xw2t,   // [64][24576]
    float* __restrict__ part)          // [16][8192][64]
{
  __shared__ bf16_t As[128 * 64];
  __shared__ bf16_t Bs[64 * 64];
  int mtile = blockIdx.x, ksp = blockIdx.y;
  int tid = threadIdx.x, lane = tid & 63, wid = tid >> 6;
  int wm = wid >> 1, wn = wid & 1;
  int sl = (lane & 7) ^ (lane >> 3);
  const size_t NN = (size_t)NROWS * NROWS;
  f32x4 acc[4][2] = {};
  for (int kt = ksp * 24; kt < ksp * 24 + 24; ++kt) {
    int kk = kt * 64;
    int ord = kk >> 13, mcol = kk & 8191;
    const bf16_t* ao = adjb + (size_t)ord * NN + (size_t)(mtile * 128) * NROWS + mcol;
    for (int j = 0; j < 4; ++j) {           // A: adj_bf rows
      int q = wid * 4 + j;
      int row = q * 8 + (lane >> 3);
      GLDS(ao + (size_t)row * NROWS + sl * 8, &As[q * 512]);
    }
    for (int j = 0; j < 2; ++j) {           // B: xw2T rows (o2)
      int q = wid * 2 + j;
      int row = q * 8 + (lane >> 3);
      GLDS(xw2t + (size_t)row * KTOT + kk + sl * 8, &Bs[q * 512]);
    }
    __syncthreads();
    for (int ks = 0; ks < 2; ++ks) {
      int psl = ((ks << 2) + (lane >> 4)) ^ (lane & 7);
      bf16x8 a[4], b[2];
      for (int f = 0; f < 4; ++f)
        a[f] = *reinterpret_cast<const bf16x8*>(&As[(wm * 64 + f * 16 + (lane & 15)) * 64 + psl * 8]);
      for (int f = 0; f < 2; ++f)
        b[f] = *reinterpret_cast<const bf16x8*>(&Bs[(wn * 32 + f * 16 + (lane & 15)) * 64 + psl * 8]);
      for (int fm = 0; fm < 4; ++fm)
        for (int fn = 0; fn < 2; ++fn)
          acc[fm][fn] = __builtin_amdgcn_mfma_f32_16x16x32_bf16(a[fm], b[fn], acc[fm][fn], 0, 0, 0);
    }
    __syncthreads();
  }
  float* pout = part + (size_t)ksp * NROWS * DOUT;
  for (int fm = 0; fm < 4; ++fm)
    for (int fn = 0; fn < 2; ++fn) {
      int o2 = wn * 32 + fn * 16 + (lane & 15);
      int n0 = mtile * 128 + wm * 64 + fm * 16 + ((lane >> 4) << 2);
      for (int j = 0; j < 4; ++j)
        pout[(size_t)(n0 + j) * DOUT + o2] = acc[fm][fn][j];
    }
}

// ---------------- K4b: sum 16 partials + b2, row log_softmax ----------------
__global__ void k_logsoftmax(const float* __restrict__ part, const float* __restrict__ b2,
                             float* __restrict__ out) {
  int wid = threadIdx.x >> 6, lane = threadIdx.x & 63;
  int n = blockIdx.x * 4 + wid;
  size_t s = (size_t)NROWS * DOUT;
  float v = b2[lane];
#pragma unroll
  for (int p = 0; p < 16; ++p)
    v += part[(size_t)p * s + (size_t)n * DOUT + lane];
  float mx = v;
  for (int d = 32; d; d >>= 1) mx = fmaxf(mx, __shfl_xor(mx, d));
  float e = expf(v - mx);
  float sum = e;
  for (int d = 32; d; d >>= 1) sum += __shfl_xor(sum, d);
  out[(size_t)n * DOUT + lane] = (v - mx) - logf(sum);
}

// ================= fallback (small ws): f32-staged kernels =================
__global__ __launch_bounds__(256) void k_gemm_h_f32(
    const float* __restrict__ adj, const bf16_t* __restrict__ xw1t,
    const float* __restrict__ b1, bf16_t* __restrict__ h)
{
  __shared__ bf16_t As[128 * 64];
  __shared__ bf16_t Bs[128 * 64];
  int d = blockIdx.x;
  int xcd = d & 7, idx = d >> 3;
  int mtile = xcd * 8 + (idx >> 3), ntile = idx & 7;
  int tid = threadIdx.x, lane = tid & 63, wid = tid >> 6;
  int wm = wid >> 1, wn = wid & 1;
  int sl = (lane & 7) ^ (lane >> 3);
  f32x4 acc[4][4] = {};
  for (int kt = 0; kt < KTOT / 64; ++kt) {
    int kk0 = kt * 64;
    int ord = kk0 >> 13, mcol = kk0 & 8191;
    for (int j = 0; j < 4; ++j) {
      int q = wid * 4 + j;
      int row = q * 8 + (lane >> 3);
      GLDS(xw1t + (size_t)(ntile * 128 + row) * KTOT + kk0 + sl * 8, &Bs[q * 512]);
    }
    const float* abase = adj + (size_t)ord * NROWS * NROWS + (size_t)(mtile * 128) * NROWS + mcol;
    bf16x8 st[4]; int mrow[4], kb[4];
    for (int i = 0; i < 4; ++i) {
      int c = i * 256 + tid;
      mrow[i] = c >> 3; kb[i] = c & 7;
      const float4* p = reinterpret_cast<const float4*>(abase + (size_t)mrow[i] * NROWS + kb[i] * 8);
      float4 v0 = p[0], v1 = p[1];
      bf16x8 o;
      o[0]=(bf16_t)v0.x; o[1]=(bf16_t)v0.y; o[2]=(bf16_t)v0.z; o[3]=(bf16_t)v0.w;
      o[4]=(bf16_t)v1.x; o[5]=(bf16_t)v1.y; o[6]=(bf16_t)v1.z; o[7]=(bf16_t)v1.w;
      st[i] = o;
    }
    for (int i = 0; i < 4; ++i)
      *reinterpret_cast<bf16x8*>(&As[mrow[i] * 64 + (kb[i] ^ (mrow[i] & 7)) * 8]) = st[i];
    __syncthreads();
    for (int ks = 0; ks < 2; ++ks) {
      int psl = ((ks << 2) + (lane >> 4)) ^ (lane & 7);
      bf16x8 a[4], b[4];
      for (int f = 0; f < 4; ++f)
        a[f] = *reinterpret_cast<const bf16x8*>(&As[(wm * 64 + f * 16 + (lane & 15)) * 64 + psl * 8]);
      for (int f = 0; f < 4; ++f)
        b[f] = *reinterpret_cast<const bf16x8*>(&Bs[(wn * 64 + f * 16 + (lane & 15)) * 64 + psl * 8]);
      for (int fm = 0; fm < 4; ++fm)
        for (int fn = 0; fn < 4; ++fn)
          acc[fm][fn] = __builtin_amdgcn_mfma_f32_16x16x32_bf16(a[fm], b[fn], acc[fm][fn], 0, 0, 0);
    }
    __syncthreads();
  }
  for (int fm = 0; fm < 4; ++fm)
    for (int fn = 0; fn < 4; ++fn) {
      int o  = ntile * 128 + wn * 64 + fn * 16 + (lane & 15);
      float bias = b1[o];
      int n0 = mtile * 128 + wm * 64 + fm * 16 + ((lane >> 4) << 2);
      for (int j = 0; j < 4; ++j) {
        float v = acc[fm][fn][j] + bias;
        v = v > 0.0f ? v : 0.0f;
        h[(size_t)(n0 + j) * DHID + o] = (bf16_t)v;
      }
    }
}

__global__ __launch_bounds__(256) void k_gemm_out_f32(
    const float* __restrict__ adj, const bf16_t* __restrict__ xw2t,
    float* __restrict__ part)          // [16][8192][64]
{
  __shared__ bf16_t As[128 * 64];
  __shared__ bf16_t Bs[64 * 64];
  int mtile = blockIdx.x, ksp = blockIdx.y;
  int tid = threadIdx.x, lane = tid & 63, wid = tid >> 6;
  int wm = wid >> 1, wn = wid & 1;
  int sl = (lane & 7) ^ (lane >> 3);
  f32x4 acc[4][2] = {};
  for (int kt = ksp * 24; kt < ksp * 24 + 24; ++kt) {
    int kk0 = kt * 64;
    int ord = kk0 >> 13, mcol = kk0 & 8191;
    for (int j = 0; j < 2; ++j) {
      int q = wid * 2 + j;
      int row = q * 8 + (lane >> 3);
      GLDS(xw2t + (size_t)row * KTOT + kk0 + sl * 8, &Bs[q * 512]);
    }
    const float* abase = adj + (size_t)ord * NROWS * NROWS + (size_t)(mtile * 128) * NROWS + mcol;
    bf16x8 st[4]; int mrow[4], kb[4];
    for (int i = 0; i < 4; ++i) {
      int c = i * 256 + tid;
      mrow[i] = c >> 3; kb[i] = c & 7;
      const float4* p = reinterpret_cast<const float4*>(abase + (size_t)mrow[i] * NROWS + kb[i] * 8);
      float4 v0 = p[0], v1 = p[1];
      bf16x8 o;
      o[0]=(bf16_t)v0.x; o[1]=(bf16_t)v0.y; o[2]=(bf16_t)v0.z; o[3]=(bf16_t)v0.w;
      o[4]=(bf16_t)v1.x; o[5]=(bf16_t)v1.y; o[6]=(bf16_t)v1.z; o[7]=(bf16_t)v1.w;
      st[i] = o;
    }
    for (int i = 0; i < 4; ++i)
      *reinterpret_cast<bf16x8*>(&As[mrow[i] * 64 + (kb[i] ^ (mrow[i] & 7)) * 8]) = st[i];
    __syncthreads();
    for (int ks = 0; ks < 2; ++ks) {
      int psl = ((ks << 2) + (lane >> 4)) ^ (lane & 7);
      bf16x8 a[4], b[2];
      for (int f = 0; f < 4; ++f)
        a[f] = *reinterpret_cast<const bf16x8*>(&As[(wm * 64 + f * 16 + (lane & 15)) * 64 + psl * 8]);
      for (int f = 0; f < 2; ++f)
        b[f] = *reinterpret_cast<const bf16x8*>(&Bs[(wn * 32 + f * 16 + (lane & 15)) * 64 + psl * 8]);
      for (int fm = 0; fm < 4; ++fm)
        for (int fn = 0; fn < 2; ++fn)
          acc[fm][fn] = __builtin_amdgcn_mfma_f32_16x16x32_bf16(a[fm], b[fn], acc[fm][fn], 0, 0, 0);
    }
    __syncthreads();
  }
  float* pout = part + (size_t)ksp * NROWS * DOUT;
  for (int fm = 0; fm < 4; ++fm)
    for (int fn = 0; fn < 2; ++fn) {
      int o2 = wn * 32 + fn * 16 + (lane & 15);
      int n0 = mtile * 128 + wm * 64 + fm * 16 + ((lane >> 4) << 2);
      for (int j = 0; j < 4; ++j)
        pout[(size_t)(n0 + j) * DOUT + o2] = acc[fm][fn][j];
    }
}

// ---------------------------------------------------------------------------
extern "C" void kernel_launch(void* const* d_in, const int* in_sizes, int n_in,
                              void* d_out, int out_size, void* d_ws, size_t ws_size,
                              hipStream_t stream) {
  const float* x   = (const float*)d_in[0];
  const float* adj = (const float*)d_in[1];
  const float* W1  = (const float*)d_in[2];
  const float* b1  = (const float*)d_in[3];
  const float* W2  = (const float*)d_in[4];
  const float* b2  = (const float*)d_in[5];
  float* out = (float*)d_out;
  char* ws = (char*)d_ws;

  const size_t ADJB_SZ  = 402653184ULL;   // 3*8192*8192*2
  const size_t NEED_OLD = 484835328ULL;   // round-8 layout
  const size_t NEED_NEW = 551944192ULL;   // + 64 MB hpart

  if (ws_size >= NEED_OLD) {
    bf16_t* adjb = (bf16_t*)(ws + 0);                  // 384 MB
    bf16_t* xb   = (bf16_t*)(ws + ADJB_SZ);            //   8 MB
    bf16_t* w1t  = (bf16_t*)(ws + ADJB_SZ + 8388608);  //   3 MB
    bf16_t* w2t  = (bf16_t*)(ws + ADJB_SZ + 11534336); // 384 KB
    bf16_t* xw1t = (bf16_t*)(ws + ADJB_SZ + 11927552); //  48 MB
    bf16_t* h    = (bf16_t*)(ws + ADJB_SZ + 62259200); //  16 MB
    bf16_t* xw2t = (bf16_t*)(ws + ADJB_SZ + 79036416); //   3 MB
    float*  hpart = (float*)(ws + ADJB_SZ + 82182144); //  64 MB (new path only)
    float*  part = (ws_size >= NEED_NEW) ? hpart
                                         : (float*)(ws + ADJB_SZ + 11927552);

    k_cvt_adj<<<2048, 256, 0, stream>>>(adj, adjb);
    k_cvt_x<<<2048, 256, 0, stream>>>(x, xb);
    k_transpose_cvt<<<dim3(16, 8, 3), 256, 0, stream>>>(W1, w1t, DIN, DHID);
    k_transpose_cvt<<<dim3(1, 16, 3), 256, 0, stream>>>(W2, w2t, DHID, DOUT);
    k_gemm_xw1<<<dim3(8, 64, 3), 256, 0, stream>>>(xb, w1t, xw1t);
    if (ws_size >= NEED_NEW) {
      k_gemm_h256<<<256, 512, 0, stream>>>(adjb, xw1t, hpart);
      k_reduce_h<<<8192, 256, 0, stream>>>(hpart, b1, h);
    } else {
      k_gemm_h128<<<512, 256, 0, stream>>>(adjb, xw1t, b1, h);
    }
    k_gemm_xw2<<<dim3(64, 3), 256, 0, stream>>>(h, w2t, xw2t);
    k_gemm_out<<<dim3(64, 16), 256, 0, stream>>>(adjb, xw2t, part);
    k_logsoftmax<<<2048, 256, 0, stream>>>(part, b2, out);
  } else {
    bf16_t* xb   = (bf16_t*)(ws + 0);
    bf16_t* w1t  = (bf16_t*)(ws + 8388608);
    bf16_t* w2t  = (bf16_t*)(ws + 11534336);
    bf16_t* xw1t = (bf16_t*)(ws + 11927552);
    bf16_t* h    = (bf16_t*)(ws + 62259200);
    bf16_t* xw2t = (bf16_t*)(ws + 79036416);
    float*  part = (float*)(ws + 11927552);

    k_cvt_x<<<2048, 256, 0, stream>>>(x, xb);
    k_transpose_cvt<<<dim3(16, 8, 3), 256, 0, stream>>>(W1, w1t, DIN, DHID);
    k_transpose_cvt<<<dim3(1, 16, 3), 256, 0, stream>>>(W2, w2t, DHID, DOUT);
    k_gemm_xw1<<<dim3(8, 64, 3), 256, 0, stream>>>(xb, w1t, xw1t);
    k_gemm_h_f32<<<512, 256, 0, stream>>>(adj, xw1t, b1, h);
    k_gemm_xw2<<<dim3(64, 3), 256, 0, stream>>>(h, w2t, xw2t);
    k_gemm_out_f32<<<dim3(64, 16), 256, 0, stream>>>(adj, xw2t, part);
    k_logsoftmax<<<2048, 256, 0, stream>>>(part, b2, out);
  }
}